// Round 4
// baseline (438.374 us; speedup 1.0000x reference)
//
#include <hip/hip_runtime.h>

// NCM via bf16-split MFMA, round 4.
// Numerics (identical to R3, which passed at absmax 0.0078):
//   x = xh+xm+xl, w = wh+wm+wl (RNE splits); products kept:
//   xh·{wh,wm,wl}, xm·{wh,wm,wl}, xl·{wh,wm}; parent bits exact -> 3 products.
// Structure (new):
//   MFMA roles swapped: A = weights [outfeat][k], B = activations [k][elem],
//   C = [outfeat rows][elem cols] -> lane holds 4 CONTIGUOUS feats for 1 elem:
//   epilogues are packed u64 LDS stores / float4 global stores.
//   Exo inputs loaded globally per-lane + split in registers (no xu LDS).
//   Single h buffer reused for h1/h2 (anti-dep barrier). LDS = 39936 B.
//   Block = 512 threads (8 waves): wave w: n0=(w&3)*16, m-tiles {2(w>>2), +1}.
//   512 blocks -> 2 blocks/CU -> 16 waves/CU (4/SIMD) vs R3's 8.
//   4 __syncthreads per node.

typedef __attribute__((ext_vector_type(8))) short bf16x8;
typedef __attribute__((ext_vector_type(4))) float f32x4;
#define MFMA16 __builtin_amdgcn_mfma_f32_16x16x32_bf16

// ws layout (u16 units), per node i (stride 33792):
//   W1' [3][64 n][96 k]  @ 0      (k 0..63 parents, 64..79 exo, 80..95 zero)
//   W2' [3][64 n][64 k]  @ 18432
//   W3' [3][16 n][64 k]  @ 30720
#define NODE_STRIDE 33792
#define W1_SPLIT    6144
#define W2_OFF      18432
#define W2_SPLIT    4096
#define W3_OFF      30720
#define W3_SPLIT    1024

__device__ inline unsigned short bf16_rne(float x) {
    unsigned u = __float_as_uint(x);
    u += 0x7fffu + ((u >> 16) & 1u);
    return (unsigned short)(u >> 16);
}
__device__ inline float bf16_tof(unsigned short h) {
    return __uint_as_float(((unsigned)h) << 16);
}
__device__ inline void split3(float x, unsigned short& h, unsigned short& m,
                              unsigned short& l) {
    h = bf16_rne(x);
    float r = x - bf16_tof(h);
    m = bf16_rne(r);
    float r2 = r - bf16_tof(m);
    l = bf16_rne(r2);
}

// ---------------- prep: split weights into ws (unchanged from R3) ----------
#define PER_NODE_ITEMS (64 * 96 + 64 * 64 + 16 * 64)  // 11264

__global__ void prep_weights(const float* __restrict__ w_r1,
                             const float* __restrict__ w_r2,
                             const float* __restrict__ w_r3,
                             const float* __restrict__ w_i1,
                             const float* __restrict__ w_i2,
                             const float* __restrict__ w_i3,
                             unsigned short* __restrict__ ws) {
    int tid = blockIdx.x * 256 + threadIdx.x;
    if (tid >= 32 * PER_NODE_ITEMS) return;
    int node = tid / PER_NODE_ITEMS;
    int r = tid - node * PER_NODE_ITEMS;
    int off, stride;
    float wv = 0.0f;
    if (r < 6144) {                       // W1': [64 n][96 k]
        int n = r / 96, k = r - n * 96;
        if (k < 64) {
            wv = (node >= 4) ? w_i1[((node - 4) * 80 + k) * 64 + n] : 0.0f;
        } else if (k < 80) {
            wv = (node < 4) ? w_r1[(node * 16 + (k - 64)) * 64 + n]
                            : w_i1[((node - 4) * 80 + k) * 64 + n];
        }
        off = n * 96 + k; stride = W1_SPLIT;
    } else if (r < 10240) {               // W2': [64][64]
        int r2 = r - 6144;
        int n = r2 >> 6, k = r2 & 63;
        wv = (node < 4) ? w_r2[(node * 64 + k) * 64 + n]
                        : w_i2[((node - 4) * 64 + k) * 64 + n];
        off = W2_OFF + n * 64 + k; stride = W2_SPLIT;
    } else {                              // W3': [16][64]
        int r3 = r - 10240;
        int n = r3 >> 6, k = r3 & 63;
        wv = (node < 4) ? w_r3[(node * 64 + k) * 16 + n]
                        : w_i3[((node - 4) * 64 + k) * 16 + n];
        off = W3_OFF + n * 64 + k; stride = W3_SPLIT;
    }
    unsigned short h, m, l;
    split3(wv, h, m, l);
    unsigned short* base = ws + node * NODE_STRIDE;
    base[off] = h;
    base[off + stride] = m;
    base[off + 2 * stride] = l;
}

// ---------------- main kernel ----------------
__global__ __launch_bounds__(512, 4) void ncm_mfma(
    const float* __restrict__ u,
    const unsigned short* __restrict__ ws,
    const float* __restrict__ b_r1, const float* __restrict__ b_r2,
    const float* __restrict__ b_r3, const float* __restrict__ b_i1,
    const float* __restrict__ b_i2, const float* __restrict__ b_i3,
    float* __restrict__ out)
{
    // ring: parent bit slots, [slot][elem][16 feats + 8 pad] (48 B rows, 16-aligned)
    __shared__ __align__(16) unsigned short ring[4][64][24];   // 12288 B
    // h: activation splits [split][elem][64 feats + 8 pad] (144 B rows)
    __shared__ __align__(16) unsigned short h[3][64][72];      // 27648 B

    const int tid = threadIdx.x;
    const int l   = tid & 63;
    const int w   = tid >> 6;        // wave 0..7
    const int lr  = l & 15;
    const int lq  = l >> 4;
    const int n0  = (w & 3) * 16;    // this wave's outfeat slice (L1/L2)
    const int m0  = (w >> 2) * 2;    // this wave's 2 M-tiles
    const long eg = (long)blockIdx.x * 64;

    for (int i = 0; i < 32; ++i) {
        __syncthreads();  // (A) ring writes from prev L3 visible; h free to rewrite

        const unsigned short* Wn = ws + i * NODE_STRIDE;
        const int nr = n0 + lr;     // weight A-row (L1/L2)

        // ---- exo global loads (issue early), both m-tiles ----
        float4 ua[2], ub[2];
        if (lq < 2) {
            #pragma unroll
            for (int mm = 0; mm < 2; ++mm) {
                const float* up = u + (eg + (m0 + mm) * 16 + lr) * 512 + i * 16 + lq * 8;
                ua[mm] = *(const float4*)up;
                ub[mm] = *(const float4*)(up + 4);
            }
        }

        // ======== L1 ========
        f32x4 acc[2] = {{0,0,0,0},{0,0,0,0}};
        {
            // A-frags: weights, 3 k-blocks x 3 splits
            bf16x8 wa[3][3];
            #pragma unroll
            for (int kb = 0; kb < 3; ++kb)
                #pragma unroll
                for (int s = 0; s < 3; ++s)
                    wa[kb][s] = *(const bf16x8*)(Wn + s * W1_SPLIT + nr * 96 + kb * 32 + lq * 8);

            if (i >= 4) {
                #pragma unroll
                for (int kb = 0; kb < 2; ++kb) {
                    const int k = kb * 32 + lq * 8;
                    const int slot = (i + (k >> 4)) & 3;
                    #pragma unroll
                    for (int mm = 0; mm < 2; ++mm) {
                        bf16x8 bits = *(const bf16x8*)&ring[slot][(m0 + mm) * 16 + lr][k & 15];
                        acc[mm] = MFMA16(wa[kb][0], bits, acc[mm], 0, 0, 0);
                        acc[mm] = MFMA16(wa[kb][1], bits, acc[mm], 0, 0, 0);
                        acc[mm] = MFMA16(wa[kb][2], bits, acc[mm], 0, 0, 0);
                    }
                }
            }
            // exo: split u in registers -> B-frags (lq>=2 lanes: zero, weights also zero)
            bf16x8 xh[2] = {}, xm[2] = {}, xl[2] = {};
            if (lq < 2) {
                #pragma unroll
                for (int mm = 0; mm < 2; ++mm) {
                    float f[8] = {ua[mm].x, ua[mm].y, ua[mm].z, ua[mm].w,
                                  ub[mm].x, ub[mm].y, ub[mm].z, ub[mm].w};
                    #pragma unroll
                    for (int j = 0; j < 8; ++j) {
                        unsigned short sh, sm, sl;
                        split3(f[j], sh, sm, sl);
                        xh[mm][j] = (short)sh; xm[mm][j] = (short)sm; xl[mm][j] = (short)sl;
                    }
                }
            }
            #pragma unroll
            for (int mm = 0; mm < 2; ++mm) {
                acc[mm] = MFMA16(wa[2][0], xh[mm], acc[mm], 0, 0, 0);
                acc[mm] = MFMA16(wa[2][1], xh[mm], acc[mm], 0, 0, 0);
                acc[mm] = MFMA16(wa[2][2], xh[mm], acc[mm], 0, 0, 0);
                acc[mm] = MFMA16(wa[2][0], xm[mm], acc[mm], 0, 0, 0);
                acc[mm] = MFMA16(wa[2][1], xm[mm], acc[mm], 0, 0, 0);
                acc[mm] = MFMA16(wa[2][2], xm[mm], acc[mm], 0, 0, 0);
                acc[mm] = MFMA16(wa[2][0], xl[mm], acc[mm], 0, 0, 0);
                acc[mm] = MFMA16(wa[2][1], xl[mm], acc[mm], 0, 0, 0);
            }
            // epilogue: bias + relu + split -> h (role h1); lane = 4 contig feats
            const float* b1p = (i < 4) ? (b_r1 + i * 64) : (b_i1 + (i - 4) * 64);
            float4 bv = *(const float4*)(b1p + n0 + lq * 4);
            float bb[4] = {bv.x, bv.y, bv.z, bv.w};
            #pragma unroll
            for (int mm = 0; mm < 2; ++mm) {
                const int e = (m0 + mm) * 16 + lr;
                unsigned long long ph = 0, pm = 0, pl = 0;
                #pragma unroll
                for (int r = 0; r < 4; ++r) {
                    float v = fmaxf(acc[mm][r] + bb[r], 0.0f);
                    unsigned short sh, sm, sl;
                    split3(v, sh, sm, sl);
                    ph |= ((unsigned long long)sh) << (16 * r);
                    pm |= ((unsigned long long)sm) << (16 * r);
                    pl |= ((unsigned long long)sl) << (16 * r);
                }
                *(unsigned long long*)&h[0][e][n0 + lq * 4] = ph;
                *(unsigned long long*)&h[1][e][n0 + lq * 4] = pm;
                *(unsigned long long*)&h[2][e][n0 + lq * 4] = pl;
            }
        }
        __syncthreads();  // (B) h1 visible

        // ======== L2 ========
        {
            bf16x8 wa[2][3];
            #pragma unroll
            for (int kb = 0; kb < 2; ++kb)
                #pragma unroll
                for (int s = 0; s < 3; ++s)
                    wa[kb][s] = *(const bf16x8*)(Wn + W2_OFF + s * W2_SPLIT + nr * 64 + kb * 32 + lq * 8);
            f32x4 acc2[2] = {{0,0,0,0},{0,0,0,0}};
            #pragma unroll
            for (int kb = 0; kb < 2; ++kb) {
                const int ko = kb * 32 + lq * 8;
                #pragma unroll
                for (int mm = 0; mm < 2; ++mm) {
                    const int e = (m0 + mm) * 16 + lr;
                    bf16x8 a0 = *(const bf16x8*)&h[0][e][ko];
                    bf16x8 a1 = *(const bf16x8*)&h[1][e][ko];
                    bf16x8 a2 = *(const bf16x8*)&h[2][e][ko];
                    acc2[mm] = MFMA16(wa[kb][0], a0, acc2[mm], 0, 0, 0);
                    acc2[mm] = MFMA16(wa[kb][1], a0, acc2[mm], 0, 0, 0);
                    acc2[mm] = MFMA16(wa[kb][2], a0, acc2[mm], 0, 0, 0);
                    acc2[mm] = MFMA16(wa[kb][0], a1, acc2[mm], 0, 0, 0);
                    acc2[mm] = MFMA16(wa[kb][1], a1, acc2[mm], 0, 0, 0);
                    acc2[mm] = MFMA16(wa[kb][2], a1, acc2[mm], 0, 0, 0);
                    acc2[mm] = MFMA16(wa[kb][0], a2, acc2[mm], 0, 0, 0);
                    acc2[mm] = MFMA16(wa[kb][1], a2, acc2[mm], 0, 0, 0);
                }
            }
            __syncthreads();  // (C) all h1 reads done before overwrite
            const float* b2p = (i < 4) ? (b_r2 + i * 64) : (b_i2 + (i - 4) * 64);
            float4 bv = *(const float4*)(b2p + n0 + lq * 4);
            float bb[4] = {bv.x, bv.y, bv.z, bv.w};
            #pragma unroll
            for (int mm = 0; mm < 2; ++mm) {
                const int e = (m0 + mm) * 16 + lr;
                unsigned long long ph = 0, pm = 0, pl = 0;
                #pragma unroll
                for (int r = 0; r < 4; ++r) {
                    float v = fmaxf(acc2[mm][r] + bb[r], 0.0f);
                    unsigned short sh, sm, sl;
                    split3(v, sh, sm, sl);
                    ph |= ((unsigned long long)sh) << (16 * r);
                    pm |= ((unsigned long long)sm) << (16 * r);
                    pl |= ((unsigned long long)sl) << (16 * r);
                }
                *(unsigned long long*)&h[0][e][n0 + lq * 4] = ph;
                *(unsigned long long*)&h[1][e][n0 + lq * 4] = pm;
                *(unsigned long long*)&h[2][e][n0 + lq * 4] = pl;
            }
        }
        __syncthreads();  // (D) h2 visible

        // ======== L3: even waves, tile t = w>>1 (elems 16t..16t+15) ========
        if ((w & 1) == 0) {
            const int t = w >> 1;
            const int e = t * 16 + lr;
            bf16x8 wa[2][3];
            #pragma unroll
            for (int kb = 0; kb < 2; ++kb)
                #pragma unroll
                for (int s = 0; s < 3; ++s)
                    wa[kb][s] = *(const bf16x8*)(Wn + W3_OFF + s * W3_SPLIT + lr * 64 + kb * 32 + lq * 8);
            f32x4 c3 = {0,0,0,0};
            #pragma unroll
            for (int kb = 0; kb < 2; ++kb) {
                const int ko = kb * 32 + lq * 8;
                bf16x8 a0 = *(const bf16x8*)&h[0][e][ko];
                bf16x8 a1 = *(const bf16x8*)&h[1][e][ko];
                bf16x8 a2 = *(const bf16x8*)&h[2][e][ko];
                c3 = MFMA16(wa[kb][0], a0, c3, 0, 0, 0);
                c3 = MFMA16(wa[kb][1], a0, c3, 0, 0, 0);
                c3 = MFMA16(wa[kb][2], a0, c3, 0, 0, 0);
                c3 = MFMA16(wa[kb][0], a1, c3, 0, 0, 0);
                c3 = MFMA16(wa[kb][1], a1, c3, 0, 0, 0);
                c3 = MFMA16(wa[kb][2], a1, c3, 0, 0, 0);
                c3 = MFMA16(wa[kb][0], a2, c3, 0, 0, 0);
                c3 = MFMA16(wa[kb][1], a2, c3, 0, 0, 0);
            }
            const float* b3p = (i < 4) ? (b_r3 + i * 16) : (b_i3 + (i - 4) * 16);
            float4 bv = *(const float4*)(b3p + lq * 4);
            float bb[4] = {bv.x, bv.y, bv.z, bv.w};
            float4 vo;
            unsigned long long pbits = 0;
            float vr[4];
            #pragma unroll
            for (int r = 0; r < 4; ++r) {
                vr[r] = c3[r] + bb[r];
                pbits |= ((unsigned long long)(vr[r] > 0.5f ? 0x3F80u : 0u)) << (16 * r);
            }
            vo.x = vr[0]; vo.y = vr[1]; vo.z = vr[2]; vo.w = vr[3];
            *(float4*)(out + (eg + e) * 512 + i * 16 + lq * 4) = vo;
            *(unsigned long long*)&ring[i & 3][e][lq * 4] = pbits;
        }
        // loop-top (A) barrier makes ring visible for node i+1
    }
}

extern "C" void kernel_launch(void* const* d_in, const int* in_sizes, int n_in,
                              void* d_out, int out_size, void* d_ws, size_t ws_size,
                              hipStream_t stream) {
    const float* u    = (const float*)d_in[0];
    const float* w_r1 = (const float*)d_in[1];
    const float* b_r1 = (const float*)d_in[2];
    const float* w_r2 = (const float*)d_in[3];
    const float* b_r2 = (const float*)d_in[4];
    const float* w_r3 = (const float*)d_in[5];
    const float* b_r3 = (const float*)d_in[6];
    const float* w_i1 = (const float*)d_in[7];
    const float* b_i1 = (const float*)d_in[8];
    const float* w_i2 = (const float*)d_in[9];
    const float* b_i2 = (const float*)d_in[10];
    const float* w_i3 = (const float*)d_in[11];
    const float* b_i3 = (const float*)d_in[12];
    float* out = (float*)d_out;
    unsigned short* ws = (unsigned short*)d_ws;

    prep_weights<<<dim3((32 * PER_NODE_ITEMS) / 256), dim3(256), 0, stream>>>(
        w_r1, w_r2, w_r3, w_i1, w_i2, w_i3, ws);

    ncm_mfma<<<dim3(512), dim3(512), 0, stream>>>(
        u, ws, b_r1, b_r2, b_r3, b_i1, b_i2, b_i3, out);
}

// Round 5
// 374.239 us; speedup vs baseline: 1.1714x; 1.1714x over previous
//
#include <hip/hip_runtime.h>

// NCM via bf16-split MFMA, round 5: barrier-free independent waves.
// Numerics identical to R3/R4 (passed, absmax 0.0078): x=xh+xm+xl, w=wh+wm+wl,
// products {hh,hm,mh,mm,hl,lh,ml,lm}; parent bits exact in bf16.
// Each wave owns 16 batch elems, walks all 32 nodes; ring/h are WAVE-PRIVATE
// LDS (intra-wave lgkmcnt ordering suffices) -> zero __syncthreads.
// MFMA roles: A=weights [feat][k], B=acts [k][elem], C=[feat][elem] (verified
// in R4) -> epilogue = 3 packed u64 LDS stores, output = float4 stores.
// Exo via Q-packing: A-pairs P1=[xh|xm],P2=[xm|xl],P3=[xh|xl] vs
// Q1=[wh|wh],Q2=[wm|wm],Q3=[wl|wh],Q4=[wl|wm] -> 8 products in 4 MFMAs.
// Weights pre-laid by prep kernel in exact per-lane b128 order (L2-resident).

typedef __attribute__((ext_vector_type(8))) short bf16x8;
typedef __attribute__((ext_vector_type(4))) float f32x4;
#define MFMA16 __builtin_amdgcn_mfma_f32_16x16x32_bf16

// ws image per node (u16 units), stride 35840:
//  W1P [s3][kb2][lq4][64 n][8 j] @ 0      (parents k = kb*32+lq*8+j)
//  W1E [q4][lq4][64 n][8 j]      @ 12288  (exo packed, k = lq*8+j in 0..31)
//  W2  [s3][kb2][lq4][64 n][8 j] @ 20480
//  W3  [s3][kb2][lq4][16 n][8 j] @ 32768
#define NODE_STRIDE 35840
#define W1E_OFF 12288
#define W2_OFF  20480
#define W3_OFF  32768

__device__ inline unsigned short bf16_rne(float x) {
    unsigned u = __float_as_uint(x);
    u += 0x7fffu + ((u >> 16) & 1u);
    return (unsigned short)(u >> 16);
}
__device__ inline float bf16_tof(unsigned short h) {
    return __uint_as_float(((unsigned)h) << 16);
}
__device__ inline void split3(float x, unsigned short& h, unsigned short& m,
                              unsigned short& l) {
    h = bf16_rne(x);
    float r = x - bf16_tof(h);
    m = bf16_rne(r);
    float r2 = r - bf16_tof(m);
    l = bf16_rne(r2);
}

// ---------------- prep ----------------
__global__ void prep_weights(const float* __restrict__ w_r1,
                             const float* __restrict__ w_r2,
                             const float* __restrict__ w_r3,
                             const float* __restrict__ w_i1,
                             const float* __restrict__ w_i2,
                             const float* __restrict__ w_i3,
                             unsigned short* __restrict__ ws) {
    int tid = blockIdx.x * 256 + threadIdx.x;
    if (tid >= 32 * NODE_STRIDE) return;
    int node = tid / NODE_STRIDE;
    int r = tid - node * NODE_STRIDE;
    unsigned short v;
    if (r < W1E_OFF) {                 // W1P
        int sk = r >> 9, rem = r & 511;
        int s = sk >> 3, kb = (sk >> 2) & 1, lq = sk & 3;
        int n = rem >> 3, j = rem & 7;
        int k = kb * 32 + lq * 8 + j;
        float wv = (node >= 4) ? w_i1[((node - 4) * 80 + k) * 64 + n] : 0.0f;
        unsigned short h, m, l;
        split3(wv, h, m, l);
        v = (s == 0) ? h : (s == 1) ? m : l;
    } else if (r < W2_OFF) {           // W1E (Q-packed exo)
        int t = r - W1E_OFF;
        int qk = t >> 9, rem = t & 511;
        int q = qk >> 2, lq = qk & 3;
        int n = rem >> 3, j = rem & 7;
        int k = lq * 8 + j;            // 0..31
        int kk = k & 15, half = k >> 4;
        float wv = (node < 4) ? w_r1[(node * 16 + kk) * 64 + n]
                              : w_i1[((node - 4) * 80 + 64 + kk) * 64 + n];
        unsigned short h, m, l;
        split3(wv, h, m, l);
        v = (q == 0) ? h
          : (q == 1) ? m
          : (q == 2) ? (half ? h : l)     // Q3 = [wl | wh]
                     : (half ? m : l);    // Q4 = [wl | wm]
    } else if (r < W3_OFF) {           // W2
        int t = r - W2_OFF;
        int sk = t >> 9, rem = t & 511;
        int s = sk >> 3, kb = (sk >> 2) & 1, lq = sk & 3;
        int n = rem >> 3, j = rem & 7;
        int k = kb * 32 + lq * 8 + j;
        float wv = (node < 4) ? w_r2[(node * 64 + k) * 64 + n]
                              : w_i2[((node - 4) * 64 + k) * 64 + n];
        unsigned short h, m, l;
        split3(wv, h, m, l);
        v = (s == 0) ? h : (s == 1) ? m : l;
    } else {                           // W3
        int t = r - W3_OFF;
        int sk = t >> 7, rem = t & 127;
        int s = sk >> 3, kb = (sk >> 2) & 1, lq = sk & 3;
        int n = rem >> 3, j = rem & 7;
        int k = kb * 32 + lq * 8 + j;
        float wv = (node < 4) ? w_r3[(node * 64 + k) * 16 + n]
                              : w_i3[((node - 4) * 64 + k) * 16 + n];
        unsigned short h, m, l;
        split3(wv, h, m, l);
        v = (s == 0) ? h : (s == 1) ? m : l;
    }
    ws[node * NODE_STRIDE + r] = v;
}

// ---------------- main ----------------
__global__ __launch_bounds__(256, 2) void ncm_mfma(
    const float* __restrict__ u,
    const unsigned short* __restrict__ ws,
    const float* __restrict__ b_r1, const float* __restrict__ b_r2,
    const float* __restrict__ b_r3, const float* __restrict__ b_i1,
    const float* __restrict__ b_i2, const float* __restrict__ b_i3,
    float* __restrict__ out)
{
    // wave-private regions; no __syncthreads anywhere
    __shared__ __align__(16) unsigned short ringS[4][4][16][16]; // [wave][slot][elem][feat]
    __shared__ __align__(16) unsigned short hS[4][3][16][72];    // [wave][split][elem][feat+pad]

    const int tid = threadIdx.x;
    const int l   = tid & 63;
    const int w   = tid >> 6;
    const int lr  = l & 15;
    const int lq  = l >> 4;
    unsigned short (*ring)[16][16] = ringS[w];
    unsigned short (*h)[16][72]    = hS[w];

    const long eg = ((long)blockIdx.x * 4 + w) * 16;
    const float* urow = u + (eg + lr) * 512 + (lq & 1) * 8;  // elem lr, feats (lq&1)*8..
    float* orow = out + (eg + lr) * 512;                      // elem lr

    for (int i = 0; i < 32; ++i) {
        const unsigned short* Wn = ws + i * NODE_STRIDE;

        // ---- exo inputs: 8 floats -> 3 bf16x8 splits -> packed P-frags ----
        float4 ua = *(const float4*)(urow + i * 16);
        float4 ub = *(const float4*)(urow + i * 16 + 4);
        bf16x8 xh8, xm8, xl8;
        {
            float f[8] = {ua.x, ua.y, ua.z, ua.w, ub.x, ub.y, ub.z, ub.w};
            #pragma unroll
            for (int j = 0; j < 8; ++j) {
                unsigned short sh, sm, sl;
                split3(f[j], sh, sm, sl);
                xh8[j] = (short)sh; xm8[j] = (short)sm; xl8[j] = (short)sl;
            }
        }
        const bool lo = (lq < 2);
        bf16x8 P1 = lo ? xh8 : xm8;
        bf16x8 P2 = lo ? xm8 : xl8;
        bf16x8 P3 = lo ? xh8 : xl8;

        // ---- parent-bit B-frags ----
        bf16x8 R0 = {}, R1 = {};
        if (i >= 4) {
            R0 = *(const bf16x8*)&ring[(i + (lq >> 1)) & 3][lr][(lq & 1) * 8];
            R1 = *(const bf16x8*)&ring[(i + 2 + (lq >> 1)) & 3][lr][(lq & 1) * 8];
        }

        const float* b1p = (i < 4) ? (b_r1 + i * 64) : (b_i1 + (i - 4) * 64);
        const float* b2p = (i < 4) ? (b_r2 + i * 64) : (b_i2 + (i - 4) * 64);
        const float* b3p = (i < 4) ? (b_r3 + i * 16) : (b_i3 + (i - 4) * 16);

        // ======== L1: 4 n-tiles, C=[feat][elem] ========
        #pragma unroll
        for (int nt = 0; nt < 4; ++nt) {
            const int fo = (nt * 16 + lr) * 8;
            f32x4 acc = {0, 0, 0, 0};
            if (i >= 4) {
                #pragma unroll
                for (int s = 0; s < 3; ++s) {
                    bf16x8 w0 = *(const bf16x8*)(Wn + ((s * 2 + 0) * 4 + lq) * 512 + fo);
                    bf16x8 w1 = *(const bf16x8*)(Wn + ((s * 2 + 1) * 4 + lq) * 512 + fo);
                    acc = MFMA16(w0, R0, acc, 0, 0, 0);
                    acc = MFMA16(w1, R1, acc, 0, 0, 0);
                }
            }
            {
                bf16x8 q1 = *(const bf16x8*)(Wn + W1E_OFF + (0 * 4 + lq) * 512 + fo);
                bf16x8 q2 = *(const bf16x8*)(Wn + W1E_OFF + (1 * 4 + lq) * 512 + fo);
                bf16x8 q3 = *(const bf16x8*)(Wn + W1E_OFF + (2 * 4 + lq) * 512 + fo);
                bf16x8 q4 = *(const bf16x8*)(Wn + W1E_OFF + (3 * 4 + lq) * 512 + fo);
                acc = MFMA16(q1, P1, acc, 0, 0, 0);
                acc = MFMA16(q2, P1, acc, 0, 0, 0);
                acc = MFMA16(q3, P3, acc, 0, 0, 0);
                acc = MFMA16(q4, P2, acc, 0, 0, 0);
            }
            // epilogue: lane = 4 contiguous feats (nt*16+lq*4..) of elem lr
            float4 bv = *(const float4*)(b1p + nt * 16 + lq * 4);
            float bb[4] = {bv.x, bv.y, bv.z, bv.w};
            unsigned long long ph = 0, pm = 0, pl = 0;
            #pragma unroll
            for (int r = 0; r < 4; ++r) {
                float v = fmaxf(acc[r] + bb[r], 0.0f);
                unsigned short sh, sm, sl;
                split3(v, sh, sm, sl);
                ph |= ((unsigned long long)sh) << (16 * r);
                pm |= ((unsigned long long)sm) << (16 * r);
                pl |= ((unsigned long long)sl) << (16 * r);
            }
            *(unsigned long long*)&h[0][lr][nt * 16 + lq * 4] = ph;
            *(unsigned long long*)&h[1][lr][nt * 16 + lq * 4] = pm;
            *(unsigned long long*)&h[2][lr][nt * 16 + lq * 4] = pl;
        }

        // ======== L2: read all h1 B-frags first, then overwrite h ========
        {
            bf16x8 H1[3][2];
            #pragma unroll
            for (int s = 0; s < 3; ++s)
                #pragma unroll
                for (int kb = 0; kb < 2; ++kb)
                    H1[s][kb] = *(const bf16x8*)&h[s][lr][kb * 32 + lq * 8];
            f32x4 a2[4];
            #pragma unroll
            for (int nt = 0; nt < 4; ++nt) {
                const int fo = (nt * 16 + lr) * 8;
                a2[nt] = (f32x4){0, 0, 0, 0};
                #pragma unroll
                for (int kb = 0; kb < 2; ++kb) {
                    bf16x8 w0 = *(const bf16x8*)(Wn + W2_OFF + ((0 * 2 + kb) * 4 + lq) * 512 + fo);
                    bf16x8 w1 = *(const bf16x8*)(Wn + W2_OFF + ((1 * 2 + kb) * 4 + lq) * 512 + fo);
                    bf16x8 w2 = *(const bf16x8*)(Wn + W2_OFF + ((2 * 2 + kb) * 4 + lq) * 512 + fo);
                    a2[nt] = MFMA16(w0, H1[0][kb], a2[nt], 0, 0, 0);
                    a2[nt] = MFMA16(w1, H1[0][kb], a2[nt], 0, 0, 0);
                    a2[nt] = MFMA16(w2, H1[0][kb], a2[nt], 0, 0, 0);
                    a2[nt] = MFMA16(w0, H1[1][kb], a2[nt], 0, 0, 0);
                    a2[nt] = MFMA16(w1, H1[1][kb], a2[nt], 0, 0, 0);
                    a2[nt] = MFMA16(w2, H1[1][kb], a2[nt], 0, 0, 0);
                    a2[nt] = MFMA16(w0, H1[2][kb], a2[nt], 0, 0, 0);
                    a2[nt] = MFMA16(w1, H1[2][kb], a2[nt], 0, 0, 0);
                }
            }
            #pragma unroll
            for (int nt = 0; nt < 4; ++nt) {
                float4 bv = *(const float4*)(b2p + nt * 16 + lq * 4);
                float bb[4] = {bv.x, bv.y, bv.z, bv.w};
                unsigned long long ph = 0, pm = 0, pl = 0;
                #pragma unroll
                for (int r = 0; r < 4; ++r) {
                    float v = fmaxf(a2[nt][r] + bb[r], 0.0f);
                    unsigned short sh, sm, sl;
                    split3(v, sh, sm, sl);
                    ph |= ((unsigned long long)sh) << (16 * r);
                    pm |= ((unsigned long long)sm) << (16 * r);
                    pl |= ((unsigned long long)sl) << (16 * r);
                }
                *(unsigned long long*)&h[0][lr][nt * 16 + lq * 4] = ph;
                *(unsigned long long*)&h[1][lr][nt * 16 + lq * 4] = pm;
                *(unsigned long long*)&h[2][lr][nt * 16 + lq * 4] = pl;
            }
        }

        // ======== L3: N=16, C=[feat][elem] ========
        {
            bf16x8 H2[3][2];
            #pragma unroll
            for (int s = 0; s < 3; ++s)
                #pragma unroll
                for (int kb = 0; kb < 2; ++kb)
                    H2[s][kb] = *(const bf16x8*)&h[s][lr][kb * 32 + lq * 8];
            f32x4 c3 = {0, 0, 0, 0};
            #pragma unroll
            for (int kb = 0; kb < 2; ++kb) {
                bf16x8 w0 = *(const bf16x8*)(Wn + W3_OFF + ((0 * 2 + kb) * 4 + lq) * 128 + lr * 8);
                bf16x8 w1 = *(const bf16x8*)(Wn + W3_OFF + ((1 * 2 + kb) * 4 + lq) * 128 + lr * 8);
                bf16x8 w2 = *(const bf16x8*)(Wn + W3_OFF + ((2 * 2 + kb) * 4 + lq) * 128 + lr * 8);
                c3 = MFMA16(w0, H2[0][kb], c3, 0, 0, 0);
                c3 = MFMA16(w1, H2[0][kb], c3, 0, 0, 0);
                c3 = MFMA16(w2, H2[0][kb], c3, 0, 0, 0);
                c3 = MFMA16(w0, H2[1][kb], c3, 0, 0, 0);
                c3 = MFMA16(w1, H2[1][kb], c3, 0, 0, 0);
                c3 = MFMA16(w2, H2[1][kb], c3, 0, 0, 0);
                c3 = MFMA16(w0, H2[2][kb], c3, 0, 0, 0);
                c3 = MFMA16(w1, H2[2][kb], c3, 0, 0, 0);
            }
            float4 bv = *(const float4*)(b3p + lq * 4);
            float bb[4] = {bv.x, bv.y, bv.z, bv.w};
            float4 vo;
            unsigned long long pbits = 0;
            float vr[4];
            #pragma unroll
            for (int r = 0; r < 4; ++r) {
                vr[r] = c3[r] + bb[r];
                pbits |= ((unsigned long long)(vr[r] > 0.5f ? 0x3F80u : 0u)) << (16 * r);
            }
            vo.x = vr[0]; vo.y = vr[1]; vo.z = vr[2]; vo.w = vr[3];
            *(float4*)(orow + i * 16 + lq * 4) = vo;
            *(unsigned long long*)&ring[i & 3][lr][lq * 4] = pbits;
        }
    }
}

extern "C" void kernel_launch(void* const* d_in, const int* in_sizes, int n_in,
                              void* d_out, int out_size, void* d_ws, size_t ws_size,
                              hipStream_t stream) {
    const float* u    = (const float*)d_in[0];
    const float* w_r1 = (const float*)d_in[1];
    const float* b_r1 = (const float*)d_in[2];
    const float* w_r2 = (const float*)d_in[3];
    const float* b_r2 = (const float*)d_in[4];
    const float* w_r3 = (const float*)d_in[5];
    const float* b_r3 = (const float*)d_in[6];
    const float* w_i1 = (const float*)d_in[7];
    const float* b_i1 = (const float*)d_in[8];
    const float* w_i2 = (const float*)d_in[9];
    const float* b_i2 = (const float*)d_in[10];
    const float* w_i3 = (const float*)d_in[11];
    const float* b_i3 = (const float*)d_in[12];
    float* out = (float*)d_out;
    unsigned short* ws = (unsigned short*)d_ws;

    prep_weights<<<dim3((32 * NODE_STRIDE) / 256), dim3(256), 0, stream>>>(
        w_r1, w_r2, w_r3, w_i1, w_i2, w_i3, ws);

    ncm_mfma<<<dim3(512), dim3(256), 0, stream>>>(
        u, ws, b_r1, b_r2, b_r3, b_i1, b_i2, b_i3, out);
}